// Round 6
// baseline (115806.799 us; speedup 1.0000x reference)
//
#include <hip/hip_runtime.h>
#include <math.h>

#define VOCAB 8000
#define EMB   512
#define HID   1024
#define SEQ_L 1024
#define G3    (3*HID)
#define NROLE 64          // recurrence roles; role wg = blockIdx/8 for blockIdx%8==0
#define GRID_R 512        // 512 WGs x 256 thr = 8 waves/CU chip-wide: all co-resident
#define POISON 0xAAAAAAAAu

typedef float v2f __attribute__((ext_vector_type(2)));
typedef float v4f __attribute__((ext_vector_type(4)));

// 16B load bypassing L1+L2 (reads the Infinity Cache coherence point)
__device__ __forceinline__ v4f ic_load4(const float* p) {
  v4f r;
  asm volatile("global_load_dwordx4 %0, %1, off sc0 sc1\n\ts_waitcnt vmcnt(0)"
               : "=v"(r) : "v"(p) : "memory");
  return r;
}
// 16B load bypassing L1 only (hits this XCD's L2 if the line is local)
__device__ __forceinline__ v4f l2_load4(const float* p) {
  v4f r;
  asm volatile("global_load_dwordx4 %0, %1, off sc0\n\ts_waitcnt vmcnt(0)"
               : "=v"(r) : "v"(p) : "memory");
  return r;
}
// store that lands in the local XCD L2 (write-through L1)
__device__ __forceinline__ void l2_storef(float* p, float v) {
  asm volatile("global_store_dword %0, %1, off sc0" :: "v"(p), "v"(v) : "memory");
}
__device__ __forceinline__ bool any_poison4(v4f v) {
  return __float_as_uint(v.x) == POISON || __float_as_uint(v.y) == POISON ||
         __float_as_uint(v.z) == POISON || __float_as_uint(v.w) == POISON;
}
// sum within each 16-lane row, VALU-only via DPP
__device__ __forceinline__ float row16_sum(float x) {
  int v = __float_as_int(x);
  x += __int_as_float(__builtin_amdgcn_update_dpp(0, v, 0xB1,  0xF, 0xF, false)); v = __float_as_int(x);
  x += __int_as_float(__builtin_amdgcn_update_dpp(0, v, 0x4E,  0xF, 0xF, false)); v = __float_as_int(x);
  x += __int_as_float(__builtin_amdgcn_update_dpp(0, v, 0x141, 0xF, 0xF, false)); v = __float_as_int(x);
  x += __int_as_float(__builtin_amdgcn_update_dpp(0, v, 0x140, 0xF, 0xF, false));
  return x;
}

// ---------------- prep: dec_in + valid mask ----------------
__global__ __launch_bounds__(1024) void prep_kernel(
    const int* __restrict__ target, const int* __restrict__ sos_p,
    const int* __restrict__ eos_p, int* __restrict__ dec_in,
    float* __restrict__ valid)
{
  int t = threadIdx.x;
  int eos = eos_p[0];
  dec_in[t] = (t == 0) ? sos_p[0] : target[t - 1];
  bool ne = (target[t] != eos);
  unsigned long long b = __ballot(ne);
  int lane = t & 63, w = t >> 6;
  __shared__ unsigned long long wb[16];
  if (lane == 0) wb[w] = b;
  __syncthreads();
  bool ok = (((~b) & ((1ull << lane) - 1ull)) == 0ull);
  for (int i = 0; i < 16; i++)
    if (i < w) ok = ok && (wb[i] == ~0ull);
  valid[t] = ok ? 1.0f : 0.0f;
}

// ---------------- fp32 NT GEMM: C[m][n] = dot(A[m][:K], B[n][:K]) + bias[n], x rowscale[m]
__global__ __launch_bounds__(256) void gemm_nt(
    const float* __restrict__ A, const int* __restrict__ idx,
    const float* __restrict__ B, const float* __restrict__ bias,
    const float* __restrict__ rowscale, float* __restrict__ C,
    int M, int N, int K)
{
  __shared__ __align__(16) float As[16][132];
  __shared__ __align__(16) float Bs[16][132];
  const int tid = threadIdx.x;
  const int bm = blockIdx.y * 128;
  const int bn = blockIdx.x * 128;
  const int tx = tid & 15, ty = tid >> 4;
  float acc[8][8];
#pragma unroll
  for (int i = 0; i < 8; i++)
#pragma unroll
    for (int jj = 0; jj < 8; jj++) acc[i][jj] = 0.f;

  for (int k0 = 0; k0 < K; k0 += 16) {
    __syncthreads();
#pragma unroll
    for (int r = 0; r < 2; r++) {
      int v = tid + 256 * r;
      int row = v >> 2;
      int kq = (v & 3) << 2;
      int m = bm + row;
      const float* abase = idx ? (A + (size_t)idx[m] * K) : (A + (size_t)m * K);
      float4 av = *(const float4*)(abase + k0 + kq);
      As[kq + 0][row] = av.x; As[kq + 1][row] = av.y;
      As[kq + 2][row] = av.z; As[kq + 3][row] = av.w;
      int n = bn + row;
      float4 bv = make_float4(0.f, 0.f, 0.f, 0.f);
      if (n < N) bv = *(const float4*)(B + (size_t)n * K + k0 + kq);
      Bs[kq + 0][row] = bv.x; Bs[kq + 1][row] = bv.y;
      Bs[kq + 2][row] = bv.z; Bs[kq + 3][row] = bv.w;
    }
    __syncthreads();
#pragma unroll
    for (int k = 0; k < 16; k++) {
      float am[8], bb[8];
      *(float4*)&am[0] = *(const float4*)&As[k][ty * 8];
      *(float4*)&am[4] = *(const float4*)&As[k][ty * 8 + 4];
      *(float4*)&bb[0] = *(const float4*)&Bs[k][tx * 8];
      *(float4*)&bb[4] = *(const float4*)&Bs[k][tx * 8 + 4];
#pragma unroll
      for (int i = 0; i < 8; i++)
#pragma unroll
        for (int jj = 0; jj < 8; jj++)
          acc[i][jj] += am[i] * bb[jj];
    }
  }
#pragma unroll
  for (int i = 0; i < 8; i++) {
    int m = bm + ty * 8 + i;
    float rs = rowscale ? rowscale[m] : 1.0f;
#pragma unroll
    for (int jj = 0; jj < 8; jj++) {
      int n = bn + tx * 8 + jj;
      if (n < N) C[(size_t)m * N + n] = (acc[i][jj] + bias[n]) * rs;
    }
  }
}

// ---------------- persistent GRU recurrence: XCD-local handoff, take 2 -------
// 64 role WGs x 256 threads. Row r (16 lanes) of WG wg computes h element
// j = wg*16+r; lane c covers k in [c*64, c*64+64) with 192 weight floats in
// VGPRs (launch_bounds(256,2) caps VGPR at 256 -- round 4 died of spills at a
// 64-VGPR cap, NOT of placement).
// Placement: 512 WGs launched; roles are blockIdx%8==0 (documented %8 XCD
// round-robin puts all 64 on ONE XCD at 2/CU, all co-resident); others exit.
// Handoff: publish = sc0 store (local L2, fast path) + atomicExch IC belt
// (ALWAYS, posted, off critical path) -> a pure-IC poll is always correct.
// Poll: l2_load4 sc0 (local-L2 hit ~200-400cy if placement holds). Safety:
// bounded pre-flight test seeds per-thread IC mode if this WG's chunks aren't
// L2-visible; in-loop 4096-spin watchdog flips a thread to sticky IC-only
// polls. Every degraded path == the round-0 IC design; no path can hang.
// gi operands prefetched one step ahead (IC latency would otherwise land on
// the shortened critical path). LDS MAC reads XOR-rotated by lane (2-way bank
// aliasing = free); weights pre-rotated at load so register indices stay
// compile-time (rule: no runtime-indexed register arrays).
__global__ __launch_bounds__(256, 2) void recur_kernel(
    const float* __restrict__ enc_whh, const float* __restrict__ enc_bhh,
    const float* __restrict__ dec_whh, const float* __restrict__ dec_bhh,
    const float* __restrict__ enc_state, const int* __restrict__ char_seq,
    const float* __restrict__ gi_enc, const float* __restrict__ gi_dec,
    float* hbuf, float* testrow)
{
  if ((blockIdx.x & 7) != 0) return;   // placement ballast: exit immediately
  const int wg  = blockIdx.x >> 3;     // role 0..63
  const int tid = threadIdx.x;
  const int c   = tid & 15;            // k-slice column within the row
  const int r   = tid >> 4;            // owned-element row 0..15
  const int j   = wg * 16 + r;         // global h index this row computes

  __shared__ __align__(16) float hLDS[HID];

  // test publish + h0 publish (both dual: L2 store + IC belt; one-time)
  if (tid < 16) {
    float* tp = &testrow[wg * 16 + tid];
    l2_storef(tp, 3.0f);
    atomicExch(tp, 3.0f);
    float v0 = enc_state[wg * 16 + tid];
    if (__float_as_uint(v0) == POISON) v0 = __uint_as_float(POISON ^ 1u);
    float* hp0 = &hbuf[wg * 16 + tid];
    l2_storef(hp0, v0);
    atomicExch(hp0, v0);
  }

  // weights -> 192 VGPRs/thread, pre-rotated by c so MAC register indices are
  // compile-time while the LDS read address carries the bank rotation
  v2f wv0[32], wv1[32], wv2[32];
#define LOADW(W)                                                              \
  {                                                                           \
    _Pragma("unroll")                                                         \
    for (int u = 0; u < 16; u++) {                                            \
      int t = (u ^ c) & 15;                                                   \
      v4f q0 = *(const v4f*)((W) + (size_t)(          j) * HID + c*64 + t*4); \
      v4f q1 = *(const v4f*)((W) + (size_t)(HID     + j) * HID + c*64 + t*4); \
      v4f q2 = *(const v4f*)((W) + (size_t)(2*HID   + j) * HID + c*64 + t*4); \
      wv0[2*u] = (v2f){q0.x,q0.y}; wv0[2*u+1] = (v2f){q0.z,q0.w};             \
      wv1[2*u] = (v2f){q1.x,q1.y}; wv1[2*u+1] = (v2f){q1.z,q1.w};             \
      wv2[2*u] = (v2f){q2.x,q2.y}; wv2[2*u+1] = (v2f){q2.z,q2.w};             \
    }                                                                         \
  }
  LOADW(enc_whh);
  float bhr = enc_bhh[j], bhz = enc_bhh[HID + j], bhn = enc_bhh[2 * HID + j];

  // bounded pre-flight: can this WG see everyone's chunks through L2?
  // (weight load above absorbs cross-WG launch skew before we poll)
  bool altIC = false;
  {
    const float* tp = testrow + 4 * tid;
    bool ok = false;
    for (int sp = 0; sp < 4096; sp++) {
      v4f t = l2_load4(tp);
      if (!any_poison4(t)) { ok = true; break; }
    }
    altIC = !ok;                       // seed IC-only mode (belt guarantees progress)
  }

  // prologue gi for step 1
  float gcr = 0.f, gcz = 0.f, gcn = 0.f; int csc = 1;
  if (c == 0) {
    gcr = gi_enc[j]; gcz = gi_enc[HID + j]; gcn = gi_enc[2 * HID + j];
    csc = char_seq[0];
  }

  for (int s = 1; s <= 2 * SEQ_L; s++) {
    if (s == SEQ_L + 1) {              // switch to decoder weights
      LOADW(dec_whh);
      bhr = dec_bhh[j]; bhz = dec_bhh[HID + j]; bhn = dec_bhh[2 * HID + j];
    }

    // poll h_{s-1}: 256 threads x 16B; L2 fast path, sticky IC fallback
    {
      const float* hp = hbuf + (size_t)(s - 1) * HID + 4 * tid;
      v4f hv;
      int sp = 0;
      for (;;) {
        if (!altIC) {
          hv = l2_load4(hp);
          if (!any_poison4(hv)) break;
          if (++sp == 4096) altIC = true;   // watchdog: never hang on L2
        } else {
          hv = ic_load4(hp);
          if (!any_poison4(hv)) break;
        }
      }
      *(v4f*)&hLDS[4 * tid] = hv;
    }
    __syncthreads();                   // the ONLY barrier per step

    // prefetch NEXT step's gi (consumed next iteration; latency hidden)
    float gnr = 0.f, gnz = 0.f, gnn = 0.f; int csn = 1;
    if (c == 0 && s < 2 * SEQ_L) {
      int sn = s + 1;
      const float* gp = (sn <= SEQ_L) ? gi_enc + (size_t)(sn - 1) * G3
                                      : gi_dec + (size_t)(sn - SEQ_L - 1) * G3;
      gnr = gp[j]; gnz = gp[HID + j]; gnn = gp[2 * HID + j];
      if (sn <= SEQ_L) csn = char_seq[sn - 1];
    }
    float hold = hLDS[j];

    // 192 MACs/thread; XOR-rotated read order -> 2-way bank aliasing (free),
    // 4 rows broadcast the same 16B chunk within each wave
    v2f a0 = {0.f, 0.f}, a1 = {0.f, 0.f}, a2 = {0.f, 0.f};
    const int cb = c << 8;             // byte base of my k-slice in hLDS
#pragma unroll
    for (int u = 0; u < 16; u++) {
      int off = cb + (((u ^ c) & 15) << 4);
      v4f h4 = *(const v4f*)((const char*)hLDS + off);
      v2f ha = {h4.x, h4.y}, hb = {h4.z, h4.w};
      a0 = __builtin_elementwise_fma(wv0[2*u],   ha, a0);
      a0 = __builtin_elementwise_fma(wv0[2*u+1], hb, a0);
      a1 = __builtin_elementwise_fma(wv1[2*u],   ha, a1);
      a1 = __builtin_elementwise_fma(wv1[2*u+1], hb, a1);
      a2 = __builtin_elementwise_fma(wv2[2*u],   ha, a2);
      a2 = __builtin_elementwise_fma(wv2[2*u+1], hb, a2);
    }
    float s0 = row16_sum(a0.x + a0.y);
    float s1 = row16_sum(a1.x + a1.y);
    float s2 = row16_sum(a2.x + a2.y);

    if (c == 0) {
      float ghr = s0 + bhr, ghz = s1 + bhz, ghn = s2 + bhn;
      float rg = __builtin_amdgcn_rcpf(1.f + __expf(-(gcr + ghr)));
      float zg = __builtin_amdgcn_rcpf(1.f + __expf(-(gcz + ghz)));
      float x = gcn + rg * ghn;
      float e = __expf(2.f * x);
      float n = 1.f - 2.f * __builtin_amdgcn_rcpf(e + 1.f);   // fast tanh
      float hnew = (1.f - zg) * n + zg * hold;
      if (s <= SEQ_L && csc == 0) hnew = hold;                // encoder mask
      if (__float_as_uint(hnew) == POISON) hnew = __uint_as_float(POISON ^ 1u);
      float* pp = &hbuf[(size_t)s * HID + j];
      l2_storef(pp, hnew);             // fast local-L2 path (coalesces: 4 lanes/wave)
      atomicExch(pp, hnew);            // IC belt (posted; makes IC polls always valid)
    }
    gcr = gnr; gcz = gnz; gcn = gnn; csc = csn;
    // no second barrier: a poller overwrites hLDS only after detecting the
    // FULL row s, which requires all 16 local publishes; each publish follows
    // its whole wave's MAC reads (DPP reduce forces wave lockstep).
  }
}

// ---------------- states output: hdec * valid ----------------
__global__ __launch_bounds__(256) void states_kernel(
    const float* __restrict__ hdec, const float* __restrict__ valid,
    float* __restrict__ out2)
{
  int i = blockIdx.x * 256 + threadIdx.x;
  out2[i] = hdec[i] * valid[i >> 10];
}

extern "C" void kernel_launch(void* const* d_in, const int* in_sizes, int n_in,
                              void* d_out, int out_size, void* d_ws, size_t ws_size,
                              hipStream_t stream)
{
  const int*   char_seq  = (const int*)  d_in[0];
  const int*   target    = (const int*)  d_in[1];
  const float* enc_state = (const float*)d_in[2];
  const float* emb       = (const float*)d_in[3];
  const float* enc_wih   = (const float*)d_in[4];
  const float* enc_whh   = (const float*)d_in[5];
  const float* enc_bih   = (const float*)d_in[6];
  const float* enc_bhh   = (const float*)d_in[7];
  const float* dec_wih   = (const float*)d_in[8];
  const float* dec_whh   = (const float*)d_in[9];
  const float* dec_bih   = (const float*)d_in[10];
  const float* dec_bhh   = (const float*)d_in[11];
  const float* out_w     = (const float*)d_in[12];
  const float* out_b     = (const float*)d_in[13];
  const int*   sos_p     = (const int*)  d_in[14];
  const int*   eos_p     = (const int*)  d_in[15];

  char* ws = (char*)d_ws;
  float* gi_enc  = (float*)ws;  ws += (size_t)SEQ_L * G3 * sizeof(float);
  float* gi_dec  = (float*)ws;  ws += (size_t)SEQ_L * G3 * sizeof(float);
  float* hbuf    = (float*)ws;  ws += (size_t)(2 * SEQ_L + 1) * HID * sizeof(float);
  float* valid   = (float*)ws;  ws += SEQ_L * sizeof(float);
  int*   dec_in  = (int*)ws;    ws += SEQ_L * sizeof(int);
  float* testrow = (float*)ws;  ws += HID * sizeof(float);

  // decode step d (1..SEQ_L) writes hbuf row SEQ_L+d  ->  hdec = hbuf[SEQ_L+1]
  float* hdec = hbuf + (size_t)(SEQ_L + 1) * HID;

  float* out_scores = (float*)d_out;
  float* out_states = out_scores + (size_t)SEQ_L * VOCAB;

  prep_kernel<<<1, 1024, 0, stream>>>(target, sos_p, eos_p, dec_in, valid);
  gemm_nt<<<dim3(G3 / 128, SEQ_L / 128), 256, 0, stream>>>(
      emb, char_seq, enc_wih, enc_bih, nullptr, gi_enc, SEQ_L, G3, EMB);
  gemm_nt<<<dim3(G3 / 128, SEQ_L / 128), 256, 0, stream>>>(
      emb, dec_in, dec_wih, dec_bih, nullptr, gi_dec, SEQ_L, G3, EMB);
  recur_kernel<<<GRID_R, 256, 0, stream>>>(
      enc_whh, enc_bhh, dec_whh, dec_bhh, enc_state, char_seq,
      gi_enc, gi_dec, hbuf, testrow);
  gemm_nt<<<dim3((VOCAB + 127) / 128, SEQ_L / 128), 256, 0, stream>>>(
      hdec, nullptr, out_w, out_b, valid, out_scores, SEQ_L, VOCAB, HID);
  states_kernel<<<(SEQ_L * HID) / 256, 256, 0, stream>>>(hdec, valid, out_states);
}

// Round 7
// 30416.055 us; speedup vs baseline: 3.8074x; 3.8074x over previous
//
#include <hip/hip_runtime.h>
#include <math.h>

#define VOCAB 8000
#define EMB   512
#define HID   1024
#define SEQ_L 1024
#define G3    (3*HID)
#define NROLE 32          // role WGs (each owns 32 h-elements); blockIdx%8==0
#define GRID_R 256        // 256 WGs x 1024 thr = 1 block/CU chip-wide
#define POISON 0xAAAAAAAAu

typedef float v2f __attribute__((ext_vector_type(2)));
typedef float v4f __attribute__((ext_vector_type(4)));

// 16B load bypassing L1+L2 (reads the Infinity Cache coherence point)
__device__ __forceinline__ v4f ic_load4(const float* p) {
  v4f r;
  asm volatile("global_load_dwordx4 %0, %1, off sc0 sc1\n\ts_waitcnt vmcnt(0)"
               : "=v"(r) : "v"(p) : "memory");
  return r;
}
// 16B load bypassing L1 only (hits this XCD's L2)
__device__ __forceinline__ v4f l2_load4(const float* p) {
  v4f r;
  asm volatile("global_load_dwordx4 %0, %1, off sc0\n\ts_waitcnt vmcnt(0)"
               : "=v"(r) : "v"(p) : "memory");
  return r;
}
// store that lands in the local XCD L2 (write-through L1)
__device__ __forceinline__ void l2_storef(float* p, float v) {
  asm volatile("global_store_dword %0, %1, off sc0" :: "v"(p), "v"(v) : "memory");
}
__device__ __forceinline__ bool any_poison4(v4f v) {
  return __float_as_uint(v.x) == POISON || __float_as_uint(v.y) == POISON ||
         __float_as_uint(v.z) == POISON || __float_as_uint(v.w) == POISON;
}
// sum within each 16-lane row, VALU-only via DPP
__device__ __forceinline__ float row16_sum(float x) {
  int v = __float_as_int(x);
  x += __int_as_float(__builtin_amdgcn_update_dpp(0, v, 0xB1,  0xF, 0xF, false)); v = __float_as_int(x);
  x += __int_as_float(__builtin_amdgcn_update_dpp(0, v, 0x4E,  0xF, 0xF, false)); v = __float_as_int(x);
  x += __int_as_float(__builtin_amdgcn_update_dpp(0, v, 0x141, 0xF, 0xF, false)); v = __float_as_int(x);
  x += __int_as_float(__builtin_amdgcn_update_dpp(0, v, 0x140, 0xF, 0xF, false));
  return x;
}
__device__ __forceinline__ float full64_sum(float x) {
  x = row16_sum(x);
  x += __shfl_xor(x, 16, 64);
  x += __shfl_xor(x, 32, 64);
  return x;
}
__device__ __forceinline__ float gru_h(float ghr, float ghz, float ghn,
                                       float gir, float giz, float gin,
                                       float hold) {
  float r = __builtin_amdgcn_rcpf(1.f + __expf(-(gir + ghr)));
  float z = __builtin_amdgcn_rcpf(1.f + __expf(-(giz + ghz)));
  float x = gin + r * ghn;
  float e = __expf(2.f * x);
  float n = 1.f - 2.f * __builtin_amdgcn_rcpf(e + 1.f);   // fast tanh
  return (1.f - z) * n + z * hold;
}

// ---------------- prep: dec_in + valid mask ----------------
__global__ __launch_bounds__(1024) void prep_kernel(
    const int* __restrict__ target, const int* __restrict__ sos_p,
    const int* __restrict__ eos_p, int* __restrict__ dec_in,
    float* __restrict__ valid)
{
  int t = threadIdx.x;
  int eos = eos_p[0];
  dec_in[t] = (t == 0) ? sos_p[0] : target[t - 1];
  bool ne = (target[t] != eos);
  unsigned long long b = __ballot(ne);
  int lane = t & 63, w = t >> 6;
  __shared__ unsigned long long wb[16];
  if (lane == 0) wb[w] = b;
  __syncthreads();
  bool ok = (((~b) & ((1ull << lane) - 1ull)) == 0ull);
  for (int i = 0; i < 16; i++)
    if (i < w) ok = ok && (wb[i] == ~0ull);
  valid[t] = ok ? 1.0f : 0.0f;
}

// ---------------- fp32 NT GEMM: C[m][n] = dot(A[m][:K], B[n][:K]) + bias[n], x rowscale[m]
__global__ __launch_bounds__(256) void gemm_nt(
    const float* __restrict__ A, const int* __restrict__ idx,
    const float* __restrict__ B, const float* __restrict__ bias,
    const float* __restrict__ rowscale, float* __restrict__ C,
    int M, int N, int K)
{
  __shared__ __align__(16) float As[16][132];
  __shared__ __align__(16) float Bs[16][132];
  const int tid = threadIdx.x;
  const int bm = blockIdx.y * 128;
  const int bn = blockIdx.x * 128;
  const int tx = tid & 15, ty = tid >> 4;
  float acc[8][8];
#pragma unroll
  for (int i = 0; i < 8; i++)
#pragma unroll
    for (int jj = 0; jj < 8; jj++) acc[i][jj] = 0.f;

  for (int k0 = 0; k0 < K; k0 += 16) {
    __syncthreads();
#pragma unroll
    for (int r = 0; r < 2; r++) {
      int v = tid + 256 * r;
      int row = v >> 2;
      int kq = (v & 3) << 2;
      int m = bm + row;
      const float* abase = idx ? (A + (size_t)idx[m] * K) : (A + (size_t)m * K);
      float4 av = *(const float4*)(abase + k0 + kq);
      As[kq + 0][row] = av.x; As[kq + 1][row] = av.y;
      As[kq + 2][row] = av.z; As[kq + 3][row] = av.w;
      int n = bn + row;
      float4 bv = make_float4(0.f, 0.f, 0.f, 0.f);
      if (n < N) bv = *(const float4*)(B + (size_t)n * K + k0 + kq);
      Bs[kq + 0][row] = bv.x; Bs[kq + 1][row] = bv.y;
      Bs[kq + 2][row] = bv.z; Bs[kq + 3][row] = bv.w;
    }
    __syncthreads();
#pragma unroll
    for (int k = 0; k < 16; k++) {
      float am[8], bb[8];
      *(float4*)&am[0] = *(const float4*)&As[k][ty * 8];
      *(float4*)&am[4] = *(const float4*)&As[k][ty * 8 + 4];
      *(float4*)&bb[0] = *(const float4*)&Bs[k][tx * 8];
      *(float4*)&bb[4] = *(const float4*)&Bs[k][tx * 8 + 4];
#pragma unroll
      for (int i = 0; i < 8; i++)
#pragma unroll
        for (int jj = 0; jj < 8; jj++)
          acc[i][jj] += am[i] * bb[jj];
    }
  }
#pragma unroll
  for (int i = 0; i < 8; i++) {
    int m = bm + ty * 8 + i;
    float rs = rowscale ? rowscale[m] : 1.0f;
#pragma unroll
    for (int jj = 0; jj < 8; jj++) {
      int n = bn + tx * 8 + jj;
      if (n < N) C[(size_t)m * N + n] = (acc[i][jj] + bias[n]) * rs;
    }
  }
}

// ---------------- persistent GRU recurrence: XCD-local, register-feasible ----
// 32 role WGs x 1024 threads (roles = blockIdx%8==0 -> one XCD at 1 block/CU
// under the documented %8 round-robin; 224 ballast WGs exit immediately, so
// there is NO multi-block-per-CU co-residency requirement -- rounds 4/6 died
// of VGPR spills from exactly that). Wave w owns TWO h elements jA=wg*32+w,
// jB=jA+16: 96 weight VGPRs/thread (+acc ~= 125, within the 128 cap that a
// 1024-thread block implies -- feasible, unlike the 192-reg designs).
// Handoff: publish = sc0 store (local L2) + atomicExch IC belt (ALWAYS,
// posted) -> pure-IC polls are always correct. Poll = l2_load4 sc0 (local L2
// hit if placement holds). Pre-flight seeds per-thread IC mode; in-loop
// 1024-spin watchdog flips a thread to sticky IC polls. Every degraded path
// == the round-0 IC design; no path hangs.
// TWO barriers/step now: with fast L2 detection the old single-barrier scheme
// races (a poller can detect a remote chunk of row s and overwrite hLDS while
// a slow local wave still reads row s-1). gi loads issue AFTER barrier A so
// a poller lane's vmcnt(0) never drains an HBM gi fetch inside the poll.
__global__ __launch_bounds__(1024) void recur_kernel(
    const float* __restrict__ enc_whh, const float* __restrict__ enc_bhh,
    const float* __restrict__ dec_whh, const float* __restrict__ dec_bhh,
    const float* __restrict__ enc_state, const int* __restrict__ char_seq,
    const float* __restrict__ gi_enc, const float* __restrict__ gi_dec,
    float* hbuf, float* testrow)
{
  if ((blockIdx.x & 7) != 0) return;   // placement ballast: exit immediately
  const int wg   = blockIdx.x >> 3;    // role 0..31
  const int tid  = threadIdx.x;
  const int lane = tid & 63;
  const int w    = tid >> 6;           // wave id
  const int jA   = wg * 32 + w;        // first owned h element
  const int jB   = jA + 16;            // second owned h element

  __shared__ __align__(16) float hLDS[HID];

  // testrow + h0 publish (dual: local-L2 store + IC belt; one-time)
  if (tid < 32) {
    float* tp = &testrow[wg * 32 + tid];
    l2_storef(tp, 3.0f);
    atomicExch(tp, 3.0f);
    float v0 = enc_state[wg * 32 + tid];
    if (__float_as_uint(v0) == POISON) v0 = __uint_as_float(POISON ^ 1u);
    float* hp0 = &hbuf[wg * 32 + tid];
    l2_storef(hp0, v0);
    atomicExch(hp0, v0);
  }
  // warm IC lines for rows 1..16 of our 32-element chunk (2 lines/row)
  if (tid >= 960 && tid < 992) {
    int q = tid - 960;
    atomicOr((unsigned*)&hbuf[(size_t)(1 + (q >> 1)) * HID + wg * 32 + (q & 1) * 16], 0u);
  }

  // weights: 2 elements x 3 gates x 16 floats/lane = 96 VGPRs/thread
  v2f wA[3][8], wB[3][8];
#define LOADW(W)                                                              \
  {                                                                           \
    _Pragma("unroll")                                                         \
    for (int g = 0; g < 3; g++) {                                             \
      const float* ra = (W) + (size_t)(g * HID + jA) * HID + lane * 16;       \
      const float* rb = (W) + (size_t)(g * HID + jB) * HID + lane * 16;       \
      _Pragma("unroll")                                                       \
      for (int u = 0; u < 4; u++) {                                           \
        v4f qa = *(const v4f*)(ra + u * 4);                                   \
        v4f qb = *(const v4f*)(rb + u * 4);                                   \
        wA[g][2*u] = (v2f){qa.x, qa.y}; wA[g][2*u+1] = (v2f){qa.z, qa.w};     \
        wB[g][2*u] = (v2f){qb.x, qb.y}; wB[g][2*u+1] = (v2f){qb.z, qb.w};     \
      }                                                                       \
    }                                                                         \
  }
  LOADW(enc_whh);
  float bA0 = enc_bhh[jA], bA1 = enc_bhh[HID + jA], bA2 = enc_bhh[2 * HID + jA];
  float bB0 = enc_bhh[jB], bB1 = enc_bhh[HID + jB], bB2 = enc_bhh[2 * HID + jB];

  // bounded pre-flight: can I see every chunk of a published row through L2?
  // (weight load above absorbs cross-WG launch skew before polling)
  bool altIC = false;
  if (tid < 256) {
    const float* tp = testrow + 4 * tid;
    bool ok = false;
    for (int sp = 0; sp < 4096; sp++) {
      v4f t = l2_load4(tp);
      if (!any_poison4(t)) { ok = true; break; }
    }
    altIC = !ok;
  }

  for (int s = 1; s <= 2 * SEQ_L; s++) {
    if (s == SEQ_L + 1) {              // switch to decoder weights
      LOADW(dec_whh);
      bA0 = dec_bhh[jA]; bA1 = dec_bhh[HID + jA]; bA2 = dec_bhh[2 * HID + jA];
      bB0 = dec_bhh[jB]; bB1 = dec_bhh[HID + jB]; bB2 = dec_bhh[2 * HID + jB];
    }
    if (tid >= 976 && tid < 978 && s + 16 <= 2 * SEQ_L)
      atomicOr((unsigned*)&hbuf[(size_t)(s + 16) * HID + wg * 32 + (tid - 976) * 16], 0u);

    // poll h_{s-1}: 256 threads x 16B; L2 fast path, sticky IC fallback
    if (tid < 256) {
      const float* hp = hbuf + (size_t)(s - 1) * HID + 4 * tid;
      v4f hv;
      int sp = 0;
      for (;;) {
        if (!altIC) {
          hv = l2_load4(hp);
          if (!any_poison4(hv)) break;
          if (++sp == 1024) altIC = true;   // watchdog: never hang on L2
        } else {
          hv = ic_load4(hp);
          if (!any_poison4(hv)) break;
        }
      }
      int us = tid ^ ((tid >> 3) & 7);
      *(v4f*)&hLDS[us * 4] = hv;
    }
    __syncthreads();                    // barrier A: hLDS ready

    // gi loads AFTER barrier A: issue now, consume after ~700cy of MAC
    float g0 = 0.f, g1 = 0.f, g2 = 0.f, g3 = 0.f, g4 = 0.f, g5 = 0.f;
    int cs = 1;
    if (lane == 0) {
      const float* gi = (s <= SEQ_L) ? (gi_enc + (size_t)(s - 1) * G3)
                                     : (gi_dec + (size_t)(s - SEQ_L - 1) * G3);
      g0 = gi[jA]; g1 = gi[HID + jA]; g2 = gi[2 * HID + jA];
      g3 = gi[jB]; g4 = gi[HID + jB]; g5 = gi[2 * HID + jB];
      if (s <= SEQ_L) cs = char_seq[s - 1];
    }
    int ujA = jA >> 2, usjA = ujA ^ ((ujA >> 3) & 7);
    int ujB = jB >> 2, usjB = ujB ^ ((ujB >> 3) & 7);
    float holdA = hLDS[usjA * 4 + (jA & 3)];
    float holdB = hLDS[usjB * 4 + (jB & 3)];

    // 96 MACs/thread on shared b128 LDS fragments (2-way bank aliasing free)
    v2f aA0 = {0.f,0.f}, aA1 = {0.f,0.f}, aA2 = {0.f,0.f};
    v2f aB0 = {0.f,0.f}, aB1 = {0.f,0.f}, aB2 = {0.f,0.f};
#pragma unroll
    for (int u = 0; u < 4; u++) {
      int uu = (lane << 2) | u, sw = uu ^ ((uu >> 3) & 7);
      v4f h4 = *(const v4f*)&hLDS[sw * 4];
      v2f ha = {h4.x, h4.y}, hb = {h4.z, h4.w};
      aA0 = __builtin_elementwise_fma(wA[0][2*u],   ha, aA0);
      aA0 = __builtin_elementwise_fma(wA[0][2*u+1], hb, aA0);
      aA1 = __builtin_elementwise_fma(wA[1][2*u],   ha, aA1);
      aA1 = __builtin_elementwise_fma(wA[1][2*u+1], hb, aA1);
      aA2 = __builtin_elementwise_fma(wA[2][2*u],   ha, aA2);
      aA2 = __builtin_elementwise_fma(wA[2][2*u+1], hb, aA2);
      aB0 = __builtin_elementwise_fma(wB[0][2*u],   ha, aB0);
      aB0 = __builtin_elementwise_fma(wB[0][2*u+1], hb, aB0);
      aB1 = __builtin_elementwise_fma(wB[1][2*u],   ha, aB1);
      aB1 = __builtin_elementwise_fma(wB[1][2*u+1], hb, aB1);
      aB2 = __builtin_elementwise_fma(wB[2][2*u],   ha, aB2);
      aB2 = __builtin_elementwise_fma(wB[2][2*u+1], hb, aB2);
    }
    float sA0 = full64_sum(aA0.x + aA0.y);
    float sA1 = full64_sum(aA1.x + aA1.y);
    float sA2 = full64_sum(aA2.x + aA2.y);
    float sB0 = full64_sum(aB0.x + aB0.y);
    float sB1 = full64_sum(aB1.x + aB1.y);
    float sB2 = full64_sum(aB2.x + aB2.y);

    if (lane == 0) {
      float hnA = gru_h(sA0 + bA0, sA1 + bA1, sA2 + bA2, g0, g1, g2, holdA);
      float hnB = gru_h(sB0 + bB0, sB1 + bB1, sB2 + bB2, g3, g4, g5, holdB);
      if (s <= SEQ_L && cs == 0) { hnA = holdA; hnB = holdB; }   // encoder mask
      if (__float_as_uint(hnA) == POISON) hnA = __uint_as_float(POISON ^ 1u);
      if (__float_as_uint(hnB) == POISON) hnB = __uint_as_float(POISON ^ 1u);
      float* pA = &hbuf[(size_t)s * HID + jA];
      float* pB = &hbuf[(size_t)s * HID + jB];
      l2_storef(pA, hnA);  atomicExch(pA, hnA);   // local fast path + IC belt
      l2_storef(pB, hnB);  atomicExch(pB, hnB);
    }
    __syncthreads();                    // barrier B: all hLDS reads done before
                                        // any poller overwrites it next step
  }
}

// ---------------- states output: hdec * valid ----------------
__global__ __launch_bounds__(256) void states_kernel(
    const float* __restrict__ hdec, const float* __restrict__ valid,
    float* __restrict__ out2)
{
  int i = blockIdx.x * 256 + threadIdx.x;
  out2[i] = hdec[i] * valid[i >> 10];
}

extern "C" void kernel_launch(void* const* d_in, const int* in_sizes, int n_in,
                              void* d_out, int out_size, void* d_ws, size_t ws_size,
                              hipStream_t stream)
{
  const int*   char_seq  = (const int*)  d_in[0];
  const int*   target    = (const int*)  d_in[1];
  const float* enc_state = (const float*)d_in[2];
  const float* emb       = (const float*)d_in[3];
  const float* enc_wih   = (const float*)d_in[4];
  const float* enc_whh   = (const float*)d_in[5];
  const float* enc_bih   = (const float*)d_in[6];
  const float* enc_bhh   = (const float*)d_in[7];
  const float* dec_wih   = (const float*)d_in[8];
  const float* dec_whh   = (const float*)d_in[9];
  const float* dec_bih   = (const float*)d_in[10];
  const float* dec_bhh   = (const float*)d_in[11];
  const float* out_w     = (const float*)d_in[12];
  const float* out_b     = (const float*)d_in[13];
  const int*   sos_p     = (const int*)  d_in[14];
  const int*   eos_p     = (const int*)  d_in[15];

  char* ws = (char*)d_ws;
  float* gi_enc  = (float*)ws;  ws += (size_t)SEQ_L * G3 * sizeof(float);
  float* gi_dec  = (float*)ws;  ws += (size_t)SEQ_L * G3 * sizeof(float);
  float* hbuf    = (float*)ws;  ws += (size_t)(2 * SEQ_L + 1) * HID * sizeof(float);
  float* valid   = (float*)ws;  ws += SEQ_L * sizeof(float);
  int*   dec_in  = (int*)ws;    ws += SEQ_L * sizeof(int);
  float* testrow = (float*)ws;  ws += HID * sizeof(float);

  // decode step d (1..SEQ_L) writes hbuf row SEQ_L+d  ->  hdec = hbuf[SEQ_L+1]
  float* hdec = hbuf + (size_t)(SEQ_L + 1) * HID;

  float* out_scores = (float*)d_out;
  float* out_states = out_scores + (size_t)SEQ_L * VOCAB;

  prep_kernel<<<1, 1024, 0, stream>>>(target, sos_p, eos_p, dec_in, valid);
  gemm_nt<<<dim3(G3 / 128, SEQ_L / 128), 256, 0, stream>>>(
      emb, char_seq, enc_wih, enc_bih, nullptr, gi_enc, SEQ_L, G3, EMB);
  gemm_nt<<<dim3(G3 / 128, SEQ_L / 128), 256, 0, stream>>>(
      emb, dec_in, dec_wih, dec_bih, nullptr, gi_dec, SEQ_L, G3, EMB);
  recur_kernel<<<GRID_R, 1024, 0, stream>>>(
      enc_whh, enc_bhh, dec_whh, dec_bhh, enc_state, char_seq,
      gi_enc, gi_dec, hbuf, testrow);
  gemm_nt<<<dim3((VOCAB + 127) / 128, SEQ_L / 128), 256, 0, stream>>>(
      hdec, nullptr, out_w, out_b, valid, out_scores, SEQ_L, VOCAB, HID);
  states_kernel<<<(SEQ_L * HID) / 256, 256, 0, stream>>>(hdec, valid, out_states);
}